// Round 1
// baseline (7894.735 us; speedup 1.0000x reference)
//
#include <hip/hip_runtime.h>
#include <math.h>

#define N_NODES 65536
#define F_DIM 512
#define H_DIM 256
#define E_EDGES 1048576
#define R_REPS 512

__device__ __forceinline__ float selu_f(float x) {
    const float SC = 1.0507009873554804934f;
    const float AL = 1.6732632423543772848f;
    return x > 0.f ? SC * x : SC * AL * expm1f(x);
}

__global__ void k_init(float* deg_s, float* deg_r, float* colsum,
                       unsigned* node_min, unsigned long long* center_min,
                       double* loss_acc) {
    int i = blockIdx.x * 256 + threadIdx.x;
    if (i < N_NODES) { deg_s[i] = 0.f; deg_r[i] = 0.f; node_min[i] = 0x7F800000u; }
    if (i < H_DIM) colsum[i] = 0.f;
    if (i < R_REPS) center_min[i] = ~0ull;
    if (i == 0) *loss_acc = 0.0;
}

__global__ void k_degree(const int* __restrict__ senders, const int* __restrict__ receivers,
                         float* __restrict__ deg_s, float* __restrict__ deg_r) {
    int e = blockIdx.x * 256 + threadIdx.x;
    if (e < E_EDGES) {
        atomicAdd(&deg_s[senders[e]], 1.f);
        atomicAdd(&deg_r[receivers[e]], 1.f);
    }
}

__global__ void k_invsqrt(float* deg_s, float* deg_r) {
    int i = blockIdx.x * 256 + threadIdx.x;
    if (i < N_NODES) {
        deg_s[i] = 1.0f / sqrtf(fmaxf(deg_s[i], 1.f));
        deg_r[i] = 1.0f / sqrtf(fmaxf(deg_r[i], 1.f));
    }
}

// X[M,256] = A[M,512] @ W[512,256] + b   (64x64 tile, 4x4 microtile)
__global__ __launch_bounds__(256) void k_gemm_xw(
    const float* __restrict__ A, const float* __restrict__ W,
    const float* __restrict__ bias, float* __restrict__ X) {
    __shared__ float As[16][64];
    __shared__ float Bs[16][64];
    const int t = threadIdx.x;
    const int tm = t >> 4, tn = t & 15;
    const int m0 = blockIdx.x * 64;
    const int n0 = blockIdx.y * 64;
    const int la_r = t >> 2;
    const int la_c = (t & 3) << 2;
    const int lb_r = t >> 4;
    const int lb_c = (t & 15) << 2;
    float acc[4][4] = {};
    for (int k0 = 0; k0 < F_DIM; k0 += 16) {
        float4 av = *(const float4*)&A[(size_t)(m0 + la_r) * F_DIM + k0 + la_c];
        As[la_c + 0][la_r] = av.x;
        As[la_c + 1][la_r] = av.y;
        As[la_c + 2][la_r] = av.z;
        As[la_c + 3][la_r] = av.w;
        *(float4*)&Bs[lb_r][lb_c] = *(const float4*)&W[(size_t)(k0 + lb_r) * H_DIM + n0 + lb_c];
        __syncthreads();
        #pragma unroll
        for (int k = 0; k < 16; ++k) {
            float4 a = *(float4*)&As[k][tm << 2];
            float4 b = *(float4*)&Bs[k][tn << 2];
            acc[0][0] += a.x * b.x; acc[0][1] += a.x * b.y; acc[0][2] += a.x * b.z; acc[0][3] += a.x * b.w;
            acc[1][0] += a.y * b.x; acc[1][1] += a.y * b.y; acc[1][2] += a.y * b.z; acc[1][3] += a.y * b.w;
            acc[2][0] += a.z * b.x; acc[2][1] += a.z * b.y; acc[2][2] += a.z * b.z; acc[2][3] += a.z * b.w;
            acc[3][0] += a.w * b.x; acc[3][1] += a.w * b.y; acc[3][2] += a.w * b.z; acc[3][3] += a.w * b.w;
        }
        __syncthreads();
    }
    float4 bv = *(const float4*)&bias[n0 + (tn << 2)];
    #pragma unroll
    for (int i = 0; i < 4; ++i) {
        float4 o;
        o.x = acc[i][0] + bv.x;
        o.y = acc[i][1] + bv.y;
        o.z = acc[i][2] + bv.z;
        o.w = acc[i][3] + bv.w;
        *(float4*)&X[(size_t)(m0 + (tm << 2) + i) * H_DIM + n0 + (tn << 2)] = o;
    }
}

// one wave per edge: Y[recv] += X[send] * inv_s[send]
__global__ __launch_bounds__(256) void k_scatter(
    const float* __restrict__ X, const int* __restrict__ senders,
    const int* __restrict__ receivers, const float* __restrict__ inv_s,
    float* __restrict__ Y) {
    int e = blockIdx.x * 4 + (threadIdx.x >> 6);
    int lane = threadIdx.x & 63;
    int s = senders[e];
    int r = receivers[e];
    float w = inv_s[s];
    float4 vx = *(const float4*)&X[(size_t)s * H_DIM + (lane << 2)];
    float* yp = &Y[(size_t)r * H_DIM + (lane << 2)];
    atomicAdd(yp + 0, vx.x * w);
    atomicAdd(yp + 1, vx.y * w);
    atomicAdd(yp + 2, vx.z * w);
    atomicAdd(yp + 3, vx.w * w);
}

__global__ void k_epilogue1(const float* __restrict__ Y, const float* __restrict__ inv_r,
                            float* __restrict__ nodes1) {
    size_t i4 = ((size_t)blockIdx.x * 256 + threadIdx.x) * 4;
    int row = (int)(i4 >> 8);
    float ir = inv_r[row];
    float4 y = *(const float4*)&Y[i4];
    float4 o;
    o.x = selu_f(y.x * ir);
    o.y = selu_f(y.y * ir);
    o.z = selu_f(y.z * ir);
    o.w = selu_f(y.w * ir);
    *(float4*)&nodes1[i4] = o;
}

__global__ __launch_bounds__(256) void k_colsum(const float* __restrict__ nodes1,
                                                float* __restrict__ colsum) {
    int t = threadIdx.x;
    size_t r0 = (size_t)blockIdx.x * 256;
    float s = 0.f;
    for (int r = 0; r < 256; ++r) s += nodes1[(r0 + r) * H_DIM + t];
    atomicAdd(&colsum[t], s);
}

__global__ void k_summary_v(const float* __restrict__ colsum, const float* __restrict__ Wb,
                            float* __restrict__ v) {
    __shared__ float s_sum[H_DIM];
    int t = threadIdx.x;
    float m = colsum[t] * (1.f / (float)N_NODES);
    s_sum[t] = 1.f / (1.f + expf(-m));
    __syncthreads();
    float acc = 0.f;
    for (int j = 0; j < H_DIM; ++j) acc += Wb[t * H_DIM + j] * s_sum[j];
    v[t] = acc;
}

// wave per row: out[row] = dot(rows[row,:], v)
__global__ __launch_bounds__(256) void k_rowdot(const float* __restrict__ rows,
                                                const float* __restrict__ v,
                                                float* __restrict__ out) {
    int row = blockIdx.x * 4 + (threadIdx.x >> 6);
    int lane = threadIdx.x & 63;
    float4 a = *(const float4*)&rows[(size_t)row * H_DIM + (lane << 2)];
    float4 vv = *(const float4*)&v[lane << 2];
    float d = a.x * vv.x + a.y * vv.y + a.z * vv.z + a.w * vv.w;
    #pragma unroll
    for (int off = 32; off; off >>= 1) d += __shfl_down(d, off);
    if (lane == 0) out[row] = d;
}

__global__ __launch_bounds__(256) void k_normalize(float* __restrict__ emb,
                                                   float* __restrict__ e2) {
    int row = blockIdx.x * 4 + (threadIdx.x >> 6);
    int lane = threadIdx.x & 63;
    float4 a = *(float4*)&emb[(size_t)row * H_DIM + (lane << 2)];
    float ss = a.x * a.x + a.y * a.y + a.z * a.z + a.w * a.w;
    #pragma unroll
    for (int off = 32; off; off >>= 1) ss += __shfl_xor(ss, off);
    float inv = 1.f / sqrtf(ss);
    a.x *= inv; a.y *= inv; a.z *= inv; a.w *= inv;
    *(float4*)&emb[(size_t)row * H_DIM + (lane << 2)] = a;
    float s2 = a.x * a.x + a.y * a.y + a.z * a.z + a.w * a.w;
    #pragma unroll
    for (int off = 32; off; off >>= 1) s2 += __shfl_xor(s2, off);
    if (lane == 0) e2[row] = s2;
}

__global__ __launch_bounds__(256) void k_c2(const float* __restrict__ centers,
                                            float* __restrict__ c2) {
    int row = blockIdx.x * 4 + (threadIdx.x >> 6);
    int lane = threadIdx.x & 63;
    float4 a = *(const float4*)&centers[(size_t)row * H_DIM + (lane << 2)];
    float ss = a.x * a.x + a.y * a.y + a.z * a.z + a.w * a.w;
    #pragma unroll
    for (int off = 32; off; off >>= 1) ss += __shfl_xor(ss, off);
    if (lane == 0) c2[row] = ss;
}

// fused emb @ centers^T with min/argmin reductions
__global__ __launch_bounds__(256) void k_cluster(
    const float* __restrict__ emb, const float* __restrict__ centers,
    const float* __restrict__ e2, const float* __restrict__ c2,
    unsigned* __restrict__ node_min, unsigned long long* __restrict__ center_min) {
    __shared__ float As[16][64];
    __shared__ float Bs[16][64];
    __shared__ unsigned s_nmin[64];
    __shared__ unsigned long long s_cmin[64];
    const int t = threadIdx.x;
    const int tm = t >> 4, tn = t & 15;
    const int m0 = blockIdx.x * 64;
    const int n0 = blockIdx.y * 64;
    const int la_r = t >> 2;
    const int la_c = (t & 3) << 2;
    float acc[4][4] = {};
    for (int k0 = 0; k0 < H_DIM; k0 += 16) {
        float4 av = *(const float4*)&emb[(size_t)(m0 + la_r) * H_DIM + k0 + la_c];
        As[la_c + 0][la_r] = av.x;
        As[la_c + 1][la_r] = av.y;
        As[la_c + 2][la_r] = av.z;
        As[la_c + 3][la_r] = av.w;
        float4 bv = *(const float4*)&centers[(size_t)(n0 + la_r) * H_DIM + k0 + la_c];
        Bs[la_c + 0][la_r] = bv.x;
        Bs[la_c + 1][la_r] = bv.y;
        Bs[la_c + 2][la_r] = bv.z;
        Bs[la_c + 3][la_r] = bv.w;
        __syncthreads();
        #pragma unroll
        for (int k = 0; k < 16; ++k) {
            float4 a = *(float4*)&As[k][tm << 2];
            float4 b = *(float4*)&Bs[k][tn << 2];
            acc[0][0] += a.x * b.x; acc[0][1] += a.x * b.y; acc[0][2] += a.x * b.z; acc[0][3] += a.x * b.w;
            acc[1][0] += a.y * b.x; acc[1][1] += a.y * b.y; acc[1][2] += a.y * b.z; acc[1][3] += a.y * b.w;
            acc[2][0] += a.z * b.x; acc[2][1] += a.z * b.y; acc[2][2] += a.z * b.z; acc[2][3] += a.z * b.w;
            acc[3][0] += a.w * b.x; acc[3][1] += a.w * b.y; acc[3][2] += a.w * b.z; acc[3][3] += a.w * b.w;
        }
        __syncthreads();
    }
    if (t < 64) { s_nmin[t] = 0x7F800000u; s_cmin[t] = ~0ull; }
    __syncthreads();
    float e2v[4], c2v[4];
    #pragma unroll
    for (int i = 0; i < 4; ++i) e2v[i] = e2[m0 + (tm << 2) + i];
    #pragma unroll
    for (int j = 0; j < 4; ++j) c2v[j] = c2[n0 + (tn << 2) + j];
    unsigned long long cbest[4] = {~0ull, ~0ull, ~0ull, ~0ull};
    #pragma unroll
    for (int i = 0; i < 4; ++i) {
        float rmin = 3.402823466e+38f;
        unsigned node = (unsigned)(m0 + (tm << 2) + i);
        #pragma unroll
        for (int j = 0; j < 4; ++j) {
            float d2 = e2v[i] + c2v[j] - 2.f * acc[i][j];
            float d = sqrtf(fmaxf(d2, 1e-12f));
            rmin = fminf(rmin, d);
            unsigned long long pk = ((unsigned long long)__float_as_uint(d) << 32) | node;
            cbest[j] = pk < cbest[j] ? pk : cbest[j];
        }
        atomicMin(&s_nmin[(tm << 2) + i], __float_as_uint(rmin));
    }
    #pragma unroll
    for (int j = 0; j < 4; ++j) atomicMin(&s_cmin[(tn << 2) + j], cbest[j]);
    __syncthreads();
    if (t < 64) {
        atomicMin(&node_min[m0 + t], s_nmin[t]);
        atomicMin(&center_min[n0 + t], s_cmin[t]);
    }
}

__global__ __launch_bounds__(256) void k_loss(const unsigned* __restrict__ node_min,
                                              double* __restrict__ acc) {
    int i = blockIdx.x * 256 + threadIdx.x;
    float s = __uint_as_float(node_min[i]);
    #pragma unroll
    for (int off = 32; off; off >>= 1) s += __shfl_down(s, off);
    __shared__ float ws[4];
    int lane = threadIdx.x & 63, w = threadIdx.x >> 6;
    if (lane == 0) ws[w] = s;
    __syncthreads();
    if (threadIdx.x == 0) {
        float tot = ws[0] + ws[1] + ws[2] + ws[3];
        atomicAdd(acc, (double)tot);
    }
}

__global__ void k_finalize(const unsigned long long* __restrict__ center_min,
                           const double* __restrict__ loss_acc,
                           float* __restrict__ rep_out, float* __restrict__ loss_out) {
    int t = blockIdx.x * 256 + threadIdx.x;
    if (t < R_REPS) rep_out[t] = (float)(unsigned)(center_min[t] & 0xFFFFFFFFull);
    if (t == 0) *loss_out = (float)(*loss_acc);
}

// fused: nodes2 row = selu(Y*inv_r), logits2[row] = dot(row, v); nodes2 never stored
__global__ __launch_bounds__(256) void k_epilogue2(const float* __restrict__ Y,
                                                   const float* __restrict__ inv_r,
                                                   const float* __restrict__ v,
                                                   float* __restrict__ out) {
    int row = blockIdx.x * 4 + (threadIdx.x >> 6);
    int lane = threadIdx.x & 63;
    float ir = inv_r[row];
    float4 a = *(const float4*)&Y[(size_t)row * H_DIM + (lane << 2)];
    a.x = selu_f(a.x * ir);
    a.y = selu_f(a.y * ir);
    a.z = selu_f(a.z * ir);
    a.w = selu_f(a.w * ir);
    float4 vv = *(const float4*)&v[lane << 2];
    float d = a.x * vv.x + a.y * vv.y + a.z * vv.z + a.w * vv.w;
    #pragma unroll
    for (int off = 32; off; off >>= 1) d += __shfl_down(d, off);
    if (lane == 0) out[row] = d;
}

extern "C" void kernel_launch(void* const* d_in, const int* in_sizes, int n_in,
                              void* d_out, int out_size, void* d_ws, size_t ws_size,
                              hipStream_t stream) {
    const float* nodes   = (const float*)d_in[0];
    const float* c_nodes = (const float*)d_in[1];
    const int* senders   = (const int*)d_in[2];
    const int* receivers = (const int*)d_in[3];
    const float* W       = (const float*)d_in[4];
    const float* bias    = (const float*)d_in[5];
    const float* Wb      = (const float*)d_in[6];
    const float* centers = (const float*)d_in[7];

    float* out = (float*)d_out;
    float* out_emb    = out;                                  // N*H
    float* out_cent   = out + (size_t)N_NODES * H_DIM;        // R*H
    float* out_rep    = out_cent + (size_t)R_REPS * H_DIM;    // R
    float* out_loss   = out_rep + R_REPS;                     // 1
    float* out_logits = out_loss + 1;                         // 2N

    char* wp = (char*)d_ws;
    float* X = (float*)wp;                      wp += (size_t)N_NODES * H_DIM * 4;
    float* Y = (float*)wp;                      wp += (size_t)N_NODES * H_DIM * 4;
    unsigned long long* center_min = (unsigned long long*)wp; wp += (size_t)R_REPS * 8;
    double* loss_acc = (double*)wp;             wp += 8;
    float* deg_s = (float*)wp;                  wp += (size_t)N_NODES * 4;
    float* deg_r = (float*)wp;                  wp += (size_t)N_NODES * 4;
    float* colsum = (float*)wp;                 wp += (size_t)H_DIM * 4;
    float* v = (float*)wp;                      wp += (size_t)H_DIM * 4;
    float* e2 = (float*)wp;                     wp += (size_t)N_NODES * 4;
    float* c2 = (float*)wp;                     wp += (size_t)R_REPS * 4;
    unsigned* node_min = (unsigned*)wp;         wp += (size_t)N_NODES * 4;

    k_init<<<N_NODES / 256, 256, 0, stream>>>(deg_s, deg_r, colsum, node_min, center_min, loss_acc);
    hipMemsetAsync(Y, 0, (size_t)N_NODES * H_DIM * 4, stream);
    k_degree<<<E_EDGES / 256, 256, 0, stream>>>(senders, receivers, deg_s, deg_r);
    k_invsqrt<<<N_NODES / 256, 256, 0, stream>>>(deg_s, deg_r);

    dim3 gg(N_NODES / 64, H_DIM / 64);
    k_gemm_xw<<<gg, 256, 0, stream>>>(nodes, W, bias, X);
    k_scatter<<<E_EDGES / 4, 256, 0, stream>>>(X, senders, receivers, deg_s, Y);
    k_epilogue1<<<(N_NODES * H_DIM / 4) / 256, 256, 0, stream>>>(Y, deg_r, out_emb);

    k_colsum<<<N_NODES / 256, 256, 0, stream>>>(out_emb, colsum);
    k_summary_v<<<1, 256, 0, stream>>>(colsum, Wb, v);
    k_rowdot<<<N_NODES / 4, 256, 0, stream>>>(out_emb, v, out_logits);
    k_normalize<<<N_NODES / 4, 256, 0, stream>>>(out_emb, e2);
    k_c2<<<R_REPS / 4, 256, 0, stream>>>(centers, c2);

    dim3 gc(N_NODES / 64, R_REPS / 64);
    k_cluster<<<gc, 256, 0, stream>>>(out_emb, centers, e2, c2, node_min, center_min);
    k_loss<<<N_NODES / 256, 256, 0, stream>>>(node_min, loss_acc);
    k_finalize<<<2, 256, 0, stream>>>(center_min, loss_acc, out_rep, out_loss);
    hipMemcpyAsync(out_cent, centers, (size_t)R_REPS * H_DIM * 4, hipMemcpyDeviceToDevice, stream);

    // GCN2 (reuse X, Y; nodes2 never materialized)
    k_gemm_xw<<<gg, 256, 0, stream>>>(c_nodes, W, bias, X);
    hipMemsetAsync(Y, 0, (size_t)N_NODES * H_DIM * 4, stream);
    k_scatter<<<E_EDGES / 4, 256, 0, stream>>>(X, senders, receivers, deg_s, Y);
    k_epilogue2<<<N_NODES / 4, 256, 0, stream>>>(Y, deg_r, v, out_logits + N_NODES);
}

// Round 3
// 1267.826 us; speedup vs baseline: 6.2270x; 6.2270x over previous
//
#include <hip/hip_runtime.h>
#include <math.h>

#define N_NODES 65536
#define F_DIM 512
#define H_DIM 256
#define E_EDGES 1048576
#define R_REPS 512

__device__ __forceinline__ float selu_f(float x) {
    const float SC = 1.0507009873554804934f;
    const float AL = 1.6732632423543772848f;
    return x > 0.f ? SC * x : SC * AL * expm1f(x);
}

__global__ void k_init(int* cnt_s, int* cnt_r, int* cursor, float* colsum,
                       unsigned* node_min, unsigned long long* center_min,
                       double* loss_acc) {
    int i = blockIdx.x * 256 + threadIdx.x;
    if (i < N_NODES) { cnt_s[i] = 0; cnt_r[i] = 0; cursor[i] = 0; node_min[i] = 0x7F800000u; }
    if (i < H_DIM) colsum[i] = 0.f;
    if (i < R_REPS) center_min[i] = ~0ull;
    if (i == 0) *loss_acc = 0.0;
}

__global__ void k_degree(const int* __restrict__ senders, const int* __restrict__ receivers,
                         int* __restrict__ cnt_s, int* __restrict__ cnt_r) {
    int e = blockIdx.x * 256 + threadIdx.x;
    if (e < E_EDGES) {
        atomicAdd(&cnt_s[senders[e]], 1);
        atomicAdd(&cnt_r[receivers[e]], 1);
    }
}

__global__ void k_invsqrt(const int* __restrict__ cnt_s, const int* __restrict__ cnt_r,
                          float* __restrict__ inv_s, float* __restrict__ inv_r) {
    int i = blockIdx.x * 256 + threadIdx.x;
    if (i < N_NODES) {
        inv_s[i] = 1.0f / sqrtf(fmaxf((float)cnt_s[i], 1.f));
        inv_r[i] = 1.0f / sqrtf(fmaxf((float)cnt_r[i], 1.f));
    }
}

// single-block hierarchical exclusive scan of cnt_r[65536] -> row_ptr[65537]
__global__ __launch_bounds__(1024) void k_scan(const int* __restrict__ cnt,
                                               int* __restrict__ row_ptr) {
    __shared__ int part[1024];
    int t = threadIdx.x;
    int base = t * 64;
    int s = 0;
    #pragma unroll 8
    for (int i = 0; i < 64; ++i) s += cnt[base + i];
    part[t] = s;
    __syncthreads();
    for (int off = 1; off < 1024; off <<= 1) {
        int other = (t >= off) ? part[t - off] : 0;
        __syncthreads();
        part[t] += other;
        __syncthreads();
    }
    int run = part[t] - s;  // exclusive prefix of this chunk
    for (int i = 0; i < 64; ++i) {
        row_ptr[base + i] = run;
        run += cnt[base + i];
    }
    if (t == 1023) row_ptr[N_NODES] = run;
}

__global__ void k_fill(const int* __restrict__ senders, const int* __restrict__ receivers,
                       const int* __restrict__ row_ptr, int* __restrict__ cursor,
                       int* __restrict__ csr_send) {
    int e = blockIdx.x * 256 + threadIdx.x;
    if (e < E_EDGES) {
        int r = receivers[e];
        int pos = atomicAdd(&cursor[r], 1);
        csr_send[row_ptr[r] + pos] = senders[e];
    }
}

// X[M,256] = (A[M,512] @ W[512,256] + b) * inv_s[row]   (64x64 tile, 4x4 microtile)
__global__ __launch_bounds__(256) void k_gemm_xw(
    const float* __restrict__ A, const float* __restrict__ W,
    const float* __restrict__ bias, const float* __restrict__ inv_s,
    float* __restrict__ X) {
    __shared__ float As[16][64];
    __shared__ float Bs[16][64];
    const int t = threadIdx.x;
    const int tm = t >> 4, tn = t & 15;
    const int m0 = blockIdx.x * 64;
    const int n0 = blockIdx.y * 64;
    const int la_r = t >> 2;
    const int la_c = (t & 3) << 2;
    const int lb_r = t >> 4;
    const int lb_c = (t & 15) << 2;
    float acc[4][4] = {};
    for (int k0 = 0; k0 < F_DIM; k0 += 16) {
        float4 av = *(const float4*)&A[(size_t)(m0 + la_r) * F_DIM + k0 + la_c];
        As[la_c + 0][la_r] = av.x;
        As[la_c + 1][la_r] = av.y;
        As[la_c + 2][la_r] = av.z;
        As[la_c + 3][la_r] = av.w;
        *(float4*)&Bs[lb_r][lb_c] = *(const float4*)&W[(size_t)(k0 + lb_r) * H_DIM + n0 + lb_c];
        __syncthreads();
        #pragma unroll
        for (int k = 0; k < 16; ++k) {
            float4 a = *(float4*)&As[k][tm << 2];
            float4 b = *(float4*)&Bs[k][tn << 2];
            acc[0][0] += a.x * b.x; acc[0][1] += a.x * b.y; acc[0][2] += a.x * b.z; acc[0][3] += a.x * b.w;
            acc[1][0] += a.y * b.x; acc[1][1] += a.y * b.y; acc[1][2] += a.y * b.z; acc[1][3] += a.y * b.w;
            acc[2][0] += a.z * b.x; acc[2][1] += a.z * b.y; acc[2][2] += a.z * b.z; acc[2][3] += a.z * b.w;
            acc[3][0] += a.w * b.x; acc[3][1] += a.w * b.y; acc[3][2] += a.w * b.z; acc[3][3] += a.w * b.w;
        }
        __syncthreads();
    }
    float4 bv = *(const float4*)&bias[n0 + (tn << 2)];
    #pragma unroll
    for (int i = 0; i < 4; ++i) {
        int row = m0 + (tm << 2) + i;
        float w = inv_s[row];
        float4 o;
        o.x = (acc[i][0] + bv.x) * w;
        o.y = (acc[i][1] + bv.y) * w;
        o.z = (acc[i][2] + bv.z) * w;
        o.w = (acc[i][3] + bv.w) * w;
        *(float4*)&X[(size_t)row * H_DIM + n0 + (tn << 2)] = o;
    }
}

// one wave per node: acc = sum over incident edges of X[sender]; fused *inv_r + selu
__global__ __launch_bounds__(256) void k_agg1(
    const float* __restrict__ X, const int* __restrict__ csr_send,
    const int* __restrict__ row_ptr, const float* __restrict__ inv_r,
    float* __restrict__ out_emb) {
    int node = blockIdx.x * 4 + (threadIdx.x >> 6);
    int lane = threadIdx.x & 63;
    int beg = row_ptr[node], end = row_ptr[node + 1];
    float4 acc = {0.f, 0.f, 0.f, 0.f};
    for (int b = beg; b < end; b += 64) {
        int n = min(64, end - b);
        int myS = (lane < n) ? csr_send[b + lane] : 0;
        for (int i = 0; i < n; ++i) {
            int s = __shfl(myS, i);
            float4 x = *(const float4*)&X[(size_t)s * H_DIM + (lane << 2)];
            acc.x += x.x; acc.y += x.y; acc.z += x.z; acc.w += x.w;
        }
    }
    float ir = inv_r[node];
    float4 o;
    o.x = selu_f(acc.x * ir);
    o.y = selu_f(acc.y * ir);
    o.z = selu_f(acc.z * ir);
    o.w = selu_f(acc.w * ir);
    *(float4*)&out_emb[(size_t)node * H_DIM + (lane << 2)] = o;
}

// GCN2: aggregate + *inv_r + selu + dot(v) fused; nodes2 never materialized
__global__ __launch_bounds__(256) void k_agg2(
    const float* __restrict__ X, const int* __restrict__ csr_send,
    const int* __restrict__ row_ptr, const float* __restrict__ inv_r,
    const float* __restrict__ v, float* __restrict__ out) {
    int node = blockIdx.x * 4 + (threadIdx.x >> 6);
    int lane = threadIdx.x & 63;
    int beg = row_ptr[node], end = row_ptr[node + 1];
    float4 acc = {0.f, 0.f, 0.f, 0.f};
    for (int b = beg; b < end; b += 64) {
        int n = min(64, end - b);
        int myS = (lane < n) ? csr_send[b + lane] : 0;
        for (int i = 0; i < n; ++i) {
            int s = __shfl(myS, i);
            float4 x = *(const float4*)&X[(size_t)s * H_DIM + (lane << 2)];
            acc.x += x.x; acc.y += x.y; acc.z += x.z; acc.w += x.w;
        }
    }
    float ir = inv_r[node];
    float4 vv = *(const float4*)&v[lane << 2];
    float d = selu_f(acc.x * ir) * vv.x + selu_f(acc.y * ir) * vv.y
            + selu_f(acc.z * ir) * vv.z + selu_f(acc.w * ir) * vv.w;
    #pragma unroll
    for (int off = 32; off; off >>= 1) d += __shfl_down(d, off);
    if (lane == 0) out[node] = d;
}

__global__ __launch_bounds__(256) void k_colsum(const float* __restrict__ nodes1,
                                                float* __restrict__ colsum) {
    int t = threadIdx.x;
    size_t r0 = (size_t)blockIdx.x * 256;
    float s = 0.f;
    for (int r = 0; r < 256; ++r) s += nodes1[(r0 + r) * H_DIM + t];
    atomicAdd(&colsum[t], s);
}

__global__ void k_summary_v(const float* __restrict__ colsum, const float* __restrict__ Wb,
                            float* __restrict__ v) {
    __shared__ float s_sum[H_DIM];
    int t = threadIdx.x;
    float m = colsum[t] * (1.f / (float)N_NODES);
    s_sum[t] = 1.f / (1.f + expf(-m));
    __syncthreads();
    float acc = 0.f;
    for (int j = 0; j < H_DIM; ++j) acc += Wb[t * H_DIM + j] * s_sum[j];
    v[t] = acc;
}

// wave per row: out[row] = dot(rows[row,:], v)
__global__ __launch_bounds__(256) void k_rowdot(const float* __restrict__ rows,
                                                const float* __restrict__ v,
                                                float* __restrict__ out) {
    int row = blockIdx.x * 4 + (threadIdx.x >> 6);
    int lane = threadIdx.x & 63;
    float4 a = *(const float4*)&rows[(size_t)row * H_DIM + (lane << 2)];
    float4 vv = *(const float4*)&v[lane << 2];
    float d = a.x * vv.x + a.y * vv.y + a.z * vv.z + a.w * vv.w;
    #pragma unroll
    for (int off = 32; off; off >>= 1) d += __shfl_down(d, off);
    if (lane == 0) out[row] = d;
}

__global__ __launch_bounds__(256) void k_normalize(float* __restrict__ emb,
                                                   float* __restrict__ e2) {
    int row = blockIdx.x * 4 + (threadIdx.x >> 6);
    int lane = threadIdx.x & 63;
    float4 a = *(float4*)&emb[(size_t)row * H_DIM + (lane << 2)];
    float ss = a.x * a.x + a.y * a.y + a.z * a.z + a.w * a.w;
    #pragma unroll
    for (int off = 32; off; off >>= 1) ss += __shfl_xor(ss, off);
    float inv = 1.f / sqrtf(ss);
    a.x *= inv; a.y *= inv; a.z *= inv; a.w *= inv;
    *(float4*)&emb[(size_t)row * H_DIM + (lane << 2)] = a;
    float s2 = a.x * a.x + a.y * a.y + a.z * a.z + a.w * a.w;
    #pragma unroll
    for (int off = 32; off; off >>= 1) s2 += __shfl_xor(s2, off);
    if (lane == 0) e2[row] = s2;
}

__global__ __launch_bounds__(256) void k_c2(const float* __restrict__ centers,
                                            float* __restrict__ c2) {
    int row = blockIdx.x * 4 + (threadIdx.x >> 6);
    int lane = threadIdx.x & 63;
    float4 a = *(const float4*)&centers[(size_t)row * H_DIM + (lane << 2)];
    float ss = a.x * a.x + a.y * a.y + a.z * a.z + a.w * a.w;
    #pragma unroll
    for (int off = 32; off; off >>= 1) ss += __shfl_xor(ss, off);
    if (lane == 0) c2[row] = ss;
}

// fused emb @ centers^T with min/argmin reductions
__global__ __launch_bounds__(256) void k_cluster(
    const float* __restrict__ emb, const float* __restrict__ centers,
    const float* __restrict__ e2, const float* __restrict__ c2,
    unsigned* __restrict__ node_min, unsigned long long* __restrict__ center_min) {
    __shared__ float As[16][64];
    __shared__ float Bs[16][64];
    __shared__ unsigned s_nmin[64];
    __shared__ unsigned long long s_cmin[64];
    const int t = threadIdx.x;
    const int tm = t >> 4, tn = t & 15;
    const int m0 = blockIdx.x * 64;
    const int n0 = blockIdx.y * 64;
    const int la_r = t >> 2;
    const int la_c = (t & 3) << 2;
    float acc[4][4] = {};
    for (int k0 = 0; k0 < H_DIM; k0 += 16) {
        float4 av = *(const float4*)&emb[(size_t)(m0 + la_r) * H_DIM + k0 + la_c];
        As[la_c + 0][la_r] = av.x;
        As[la_c + 1][la_r] = av.y;
        As[la_c + 2][la_r] = av.z;
        As[la_c + 3][la_r] = av.w;
        float4 bv = *(const float4*)&centers[(size_t)(n0 + la_r) * H_DIM + k0 + la_c];
        Bs[la_c + 0][la_r] = bv.x;
        Bs[la_c + 1][la_r] = bv.y;
        Bs[la_c + 2][la_r] = bv.z;
        Bs[la_c + 3][la_r] = bv.w;
        __syncthreads();
        #pragma unroll
        for (int k = 0; k < 16; ++k) {
            float4 a = *(float4*)&As[k][tm << 2];
            float4 b = *(float4*)&Bs[k][tn << 2];
            acc[0][0] += a.x * b.x; acc[0][1] += a.x * b.y; acc[0][2] += a.x * b.z; acc[0][3] += a.x * b.w;
            acc[1][0] += a.y * b.x; acc[1][1] += a.y * b.y; acc[1][2] += a.y * b.z; acc[1][3] += a.y * b.w;
            acc[2][0] += a.z * b.x; acc[2][1] += a.z * b.y; acc[2][2] += a.z * b.z; acc[2][3] += a.z * b.w;
            acc[3][0] += a.w * b.x; acc[3][1] += a.w * b.y; acc[3][2] += a.w * b.z; acc[3][3] += a.w * b.w;
        }
        __syncthreads();
    }
    if (t < 64) { s_nmin[t] = 0x7F800000u; s_cmin[t] = ~0ull; }
    __syncthreads();
    float e2v[4], c2v[4];
    #pragma unroll
    for (int i = 0; i < 4; ++i) e2v[i] = e2[m0 + (tm << 2) + i];
    #pragma unroll
    for (int j = 0; j < 4; ++j) c2v[j] = c2[n0 + (tn << 2) + j];
    unsigned long long cbest[4] = {~0ull, ~0ull, ~0ull, ~0ull};
    #pragma unroll
    for (int i = 0; i < 4; ++i) {
        float rmin = 3.402823466e+38f;
        unsigned node = (unsigned)(m0 + (tm << 2) + i);
        #pragma unroll
        for (int j = 0; j < 4; ++j) {
            float d2 = e2v[i] + c2v[j] - 2.f * acc[i][j];
            float d = sqrtf(fmaxf(d2, 1e-12f));
            rmin = fminf(rmin, d);
            unsigned long long pk = ((unsigned long long)__float_as_uint(d) << 32) | node;
            cbest[j] = pk < cbest[j] ? pk : cbest[j];
        }
        atomicMin(&s_nmin[(tm << 2) + i], __float_as_uint(rmin));
    }
    #pragma unroll
    for (int j = 0; j < 4; ++j) atomicMin(&s_cmin[(tn << 2) + j], cbest[j]);
    __syncthreads();
    if (t < 64) {
        atomicMin(&node_min[m0 + t], s_nmin[t]);
        atomicMin(&center_min[n0 + t], s_cmin[t]);
    }
}

__global__ __launch_bounds__(256) void k_loss(const unsigned* __restrict__ node_min,
                                              double* __restrict__ acc) {
    int i = blockIdx.x * 256 + threadIdx.x;
    float s = __uint_as_float(node_min[i]);
    #pragma unroll
    for (int off = 32; off; off >>= 1) s += __shfl_down(s, off);
    __shared__ float ws[4];
    int lane = threadIdx.x & 63, w = threadIdx.x >> 6;
    if (lane == 0) ws[w] = s;
    __syncthreads();
    if (threadIdx.x == 0) {
        float tot = ws[0] + ws[1] + ws[2] + ws[3];
        atomicAdd(acc, (double)tot);
    }
}

__global__ void k_finalize(const unsigned long long* __restrict__ center_min,
                           const double* __restrict__ loss_acc,
                           float* __restrict__ rep_out, float* __restrict__ loss_out) {
    int t = blockIdx.x * 256 + threadIdx.x;
    if (t < R_REPS) rep_out[t] = (float)(unsigned)(center_min[t] & 0xFFFFFFFFull);
    if (t == 0) *loss_out = (float)(*loss_acc);
}

extern "C" void kernel_launch(void* const* d_in, const int* in_sizes, int n_in,
                              void* d_out, int out_size, void* d_ws, size_t ws_size,
                              hipStream_t stream) {
    const float* nodes   = (const float*)d_in[0];
    const float* c_nodes = (const float*)d_in[1];
    const int* senders   = (const int*)d_in[2];
    const int* receivers = (const int*)d_in[3];
    const float* W       = (const float*)d_in[4];
    const float* bias    = (const float*)d_in[5];
    const float* Wb      = (const float*)d_in[6];
    const float* centers = (const float*)d_in[7];

    float* out = (float*)d_out;
    float* out_emb    = out;                                  // N*H
    float* out_cent   = out + (size_t)N_NODES * H_DIM;        // R*H
    float* out_rep    = out_cent + (size_t)R_REPS * H_DIM;    // R
    float* out_loss   = out_rep + R_REPS;                     // 1
    float* out_logits = out_loss + 1;                         // 2N

    // ---- workspace layout: 8-byte-typed scratch FIRST (alignment), then 4-byte arrays ----
    char* wp = (char*)d_ws;
    unsigned long long* center_min = (unsigned long long*)wp; wp += (size_t)R_REPS * 8;
    double* loss_acc = (double*)wp;             wp += 8;
    float* X = (float*)wp;                      wp += (size_t)N_NODES * H_DIM * 4;
    int* csr_send = (int*)wp;                   wp += (size_t)E_EDGES * 4;
    int* row_ptr = (int*)wp;                    wp += (size_t)(N_NODES + 2) * 4;  // padded, 8B multiple
    int* cursor = (int*)wp;                     wp += (size_t)N_NODES * 4;
    int* cnt_s = (int*)wp;                      wp += (size_t)N_NODES * 4;
    int* cnt_r = (int*)wp;                      wp += (size_t)N_NODES * 4;
    float* inv_s = (float*)wp;                  wp += (size_t)N_NODES * 4;
    float* inv_r = (float*)wp;                  wp += (size_t)N_NODES * 4;
    float* colsum = (float*)wp;                 wp += (size_t)H_DIM * 4;
    float* v = (float*)wp;                      wp += (size_t)H_DIM * 4;
    float* e2 = (float*)wp;                     wp += (size_t)N_NODES * 4;
    float* c2 = (float*)wp;                     wp += (size_t)R_REPS * 4;
    unsigned* node_min = (unsigned*)wp;         wp += (size_t)N_NODES * 4;

    k_init<<<N_NODES / 256, 256, 0, stream>>>(cnt_s, cnt_r, cursor, colsum, node_min, center_min, loss_acc);
    k_degree<<<E_EDGES / 256, 256, 0, stream>>>(senders, receivers, cnt_s, cnt_r);
    k_invsqrt<<<N_NODES / 256, 256, 0, stream>>>(cnt_s, cnt_r, inv_s, inv_r);
    k_scan<<<1, 1024, 0, stream>>>(cnt_r, row_ptr);
    k_fill<<<E_EDGES / 256, 256, 0, stream>>>(senders, receivers, row_ptr, cursor, csr_send);

    dim3 gg(N_NODES / 64, H_DIM / 64);
    // GCN1
    k_gemm_xw<<<gg, 256, 0, stream>>>(nodes, W, bias, inv_s, X);
    k_agg1<<<N_NODES / 4, 256, 0, stream>>>(X, csr_send, row_ptr, inv_r, out_emb);

    k_colsum<<<N_NODES / 256, 256, 0, stream>>>(out_emb, colsum);
    k_summary_v<<<1, 256, 0, stream>>>(colsum, Wb, v);
    k_rowdot<<<N_NODES / 4, 256, 0, stream>>>(out_emb, v, out_logits);
    k_normalize<<<N_NODES / 4, 256, 0, stream>>>(out_emb, e2);
    k_c2<<<R_REPS / 4, 256, 0, stream>>>(centers, c2);

    dim3 gc(N_NODES / 64, R_REPS / 64);
    k_cluster<<<gc, 256, 0, stream>>>(out_emb, centers, e2, c2, node_min, center_min);
    k_loss<<<N_NODES / 256, 256, 0, stream>>>(node_min, loss_acc);
    k_finalize<<<2, 256, 0, stream>>>(center_min, loss_acc, out_rep, out_loss);
    hipMemcpyAsync(out_cent, centers, (size_t)R_REPS * H_DIM * 4, hipMemcpyDeviceToDevice, stream);

    // GCN2 (reuse X; nodes2 never materialized)
    k_gemm_xw<<<gg, 256, 0, stream>>>(c_nodes, W, bias, inv_s, X);
    k_agg2<<<N_NODES / 4, 256, 0, stream>>>(X, csr_send, row_ptr, inv_r, v, out_logits + N_NODES);
}

// Round 4
// 1175.292 us; speedup vs baseline: 6.7173x; 1.0787x over previous
//
#include <hip/hip_runtime.h>
#include <math.h>

#define N_NODES 65536
#define F_DIM 512
#define H_DIM 256
#define E_EDGES 1048576
#define R_REPS 512

__device__ __forceinline__ float selu_f(float x) {
    const float SC = 1.0507009873554804934f;
    const float AL = 1.6732632423543772848f;
    return x > 0.f ? SC * x : SC * AL * expm1f(x);
}

__global__ void k_init(int* cnt_s, int* cnt_r, int* cursor, float* colsum,
                       unsigned* node_min, unsigned long long* center_min,
                       double* loss_acc) {
    int i = blockIdx.x * 256 + threadIdx.x;
    if (i < N_NODES) { cnt_s[i] = 0; cnt_r[i] = 0; cursor[i] = 0; node_min[i] = 0x7F800000u; }
    if (i < H_DIM) colsum[i] = 0.f;
    if (i < R_REPS) center_min[i] = ~0ull;
    if (i == 0) *loss_acc = 0.0;
}

__global__ void k_degree(const int* __restrict__ senders, const int* __restrict__ receivers,
                         int* __restrict__ cnt_s, int* __restrict__ cnt_r) {
    int e = blockIdx.x * 256 + threadIdx.x;
    if (e < E_EDGES) {
        atomicAdd(&cnt_s[senders[e]], 1);
        atomicAdd(&cnt_r[receivers[e]], 1);
    }
}

__global__ void k_invsqrt(const int* __restrict__ cnt_s, const int* __restrict__ cnt_r,
                          float* __restrict__ inv_s, float* __restrict__ inv_r) {
    int i = blockIdx.x * 256 + threadIdx.x;
    if (i < N_NODES) {
        inv_s[i] = 1.0f / sqrtf(fmaxf((float)cnt_s[i], 1.f));
        inv_r[i] = 1.0f / sqrtf(fmaxf((float)cnt_r[i], 1.f));
    }
}

// single-block hierarchical exclusive scan of cnt_r[65536] -> row_ptr[65537]
__global__ __launch_bounds__(1024) void k_scan(const int* __restrict__ cnt,
                                               int* __restrict__ row_ptr) {
    __shared__ int part[1024];
    int t = threadIdx.x;
    int base = t * 64;
    int s = 0;
    #pragma unroll 8
    for (int i = 0; i < 64; ++i) s += cnt[base + i];
    part[t] = s;
    __syncthreads();
    for (int off = 1; off < 1024; off <<= 1) {
        int other = (t >= off) ? part[t - off] : 0;
        __syncthreads();
        part[t] += other;
        __syncthreads();
    }
    int run = part[t] - s;
    for (int i = 0; i < 64; ++i) {
        row_ptr[base + i] = run;
        run += cnt[base + i];
    }
    if (t == 1023) row_ptr[N_NODES] = run;
}

__global__ void k_fill(const int* __restrict__ senders, const int* __restrict__ receivers,
                       const int* __restrict__ row_ptr, int* __restrict__ cursor,
                       int* __restrict__ csr_send) {
    int e = blockIdx.x * 256 + threadIdx.x;
    if (e < E_EDGES) {
        int r = receivers[e];
        int pos = atomicAdd(&cursor[r], 1);
        csr_send[row_ptr[r] + pos] = senders[e];
    }
}

#define FMA_ROW(accv, s, bv) accv.x += (s)*(bv).x; accv.y += (s)*(bv).y; accv.z += (s)*(bv).z; accv.w += (s)*(bv).w;
#define MT(ih, jh, av, bv) \
    FMA_ROW(acc[ih][jh][0], (av).x, bv) \
    FMA_ROW(acc[ih][jh][1], (av).y, bv) \
    FMA_ROW(acc[ih][jh][2], (av).z, bv) \
    FMA_ROW(acc[ih][jh][3], (av).w, bv)

// X[128-tile, 128-tile] = (A @ W + b) * inv_s[row]; 128x128 tile, 8x8 split microtile
__global__ __launch_bounds__(256) void k_gemm128(
    const float* __restrict__ A, const float* __restrict__ W,
    const float* __restrict__ bias, const float* __restrict__ inv_s,
    float* __restrict__ X) {
    __shared__ float As[16][132];
    __shared__ float Bs[16][132];
    const int t = threadIdx.x;
    const int tm = t >> 4, tn = t & 15;
    const int m0 = blockIdx.x * 128;
    const int n0 = blockIdx.y * 128;
    const int sm = t >> 1;            // A-stage row 0..127
    const int sk = (t & 1) << 3;      // 0 or 8
    const int bk = t >> 5;            // 0..7
    const int bn = (t & 31) << 2;     // 0..124
    float4 acc[2][2][4] = {};
    const float* Arow = A + (size_t)(m0 + sm) * F_DIM;
    for (int k0 = 0; k0 < F_DIM; k0 += 16) {
        float4 va = *(const float4*)&Arow[k0 + sk];
        float4 vb = *(const float4*)&Arow[k0 + sk + 4];
        As[sk + 0][sm] = va.x; As[sk + 1][sm] = va.y; As[sk + 2][sm] = va.z; As[sk + 3][sm] = va.w;
        As[sk + 4][sm] = vb.x; As[sk + 5][sm] = vb.y; As[sk + 6][sm] = vb.z; As[sk + 7][sm] = vb.w;
        *(float4*)&Bs[bk][bn]     = *(const float4*)&W[(size_t)(k0 + bk) * H_DIM + n0 + bn];
        *(float4*)&Bs[bk + 8][bn] = *(const float4*)&W[(size_t)(k0 + bk + 8) * H_DIM + n0 + bn];
        __syncthreads();
        #pragma unroll
        for (int k = 0; k < 16; ++k) {
            float4 a0 = *(float4*)&As[k][tm << 2];
            float4 a1 = *(float4*)&As[k][64 + (tm << 2)];
            float4 b0 = *(float4*)&Bs[k][tn << 2];
            float4 b1 = *(float4*)&Bs[k][64 + (tn << 2)];
            MT(0, 0, a0, b0) MT(0, 1, a0, b1) MT(1, 0, a1, b0) MT(1, 1, a1, b1)
        }
        __syncthreads();
    }
    float4 bv[2];
    bv[0] = *(const float4*)&bias[n0 + (tn << 2)];
    bv[1] = *(const float4*)&bias[n0 + 64 + (tn << 2)];
    #pragma unroll
    for (int ih = 0; ih < 2; ++ih)
        #pragma unroll
        for (int i = 0; i < 4; ++i) {
            int row = m0 + ih * 64 + (tm << 2) + i;
            float w = inv_s[row];
            #pragma unroll
            for (int jh = 0; jh < 2; ++jh) {
                float4 o;
                o.x = (acc[ih][jh][i].x + bv[jh].x) * w;
                o.y = (acc[ih][jh][i].y + bv[jh].y) * w;
                o.z = (acc[ih][jh][i].z + bv[jh].z) * w;
                o.w = (acc[ih][jh][i].w + bv[jh].w) * w;
                *(float4*)&X[(size_t)row * H_DIM + n0 + jh * 64 + (tn << 2)] = o;
            }
        }
}

// one wave per node: acc = sum over incident edges of X[sender]; fused *inv_r + selu
__global__ __launch_bounds__(256) void k_agg1(
    const float* __restrict__ X, const int* __restrict__ csr_send,
    const int* __restrict__ row_ptr, const float* __restrict__ inv_r,
    float* __restrict__ out_emb) {
    int node = blockIdx.x * 4 + (threadIdx.x >> 6);
    int lane = threadIdx.x & 63;
    int beg = row_ptr[node], end = row_ptr[node + 1];
    float4 acc = {0.f, 0.f, 0.f, 0.f};
    for (int b = beg; b < end; b += 64) {
        int n = min(64, end - b);
        int myS = (lane < n) ? csr_send[b + lane] : 0;
        for (int i = 0; i < n; ++i) {
            int s = __shfl(myS, i);
            float4 x = *(const float4*)&X[(size_t)s * H_DIM + (lane << 2)];
            acc.x += x.x; acc.y += x.y; acc.z += x.z; acc.w += x.w;
        }
    }
    float ir = inv_r[node];
    float4 o;
    o.x = selu_f(acc.x * ir);
    o.y = selu_f(acc.y * ir);
    o.z = selu_f(acc.z * ir);
    o.w = selu_f(acc.w * ir);
    *(float4*)&out_emb[(size_t)node * H_DIM + (lane << 2)] = o;
}

// GCN2: aggregate + *inv_r + selu + dot(v) fused; nodes2 never materialized
__global__ __launch_bounds__(256) void k_agg2(
    const float* __restrict__ X, const int* __restrict__ csr_send,
    const int* __restrict__ row_ptr, const float* __restrict__ inv_r,
    const float* __restrict__ v, float* __restrict__ out) {
    int node = blockIdx.x * 4 + (threadIdx.x >> 6);
    int lane = threadIdx.x & 63;
    int beg = row_ptr[node], end = row_ptr[node + 1];
    float4 acc = {0.f, 0.f, 0.f, 0.f};
    for (int b = beg; b < end; b += 64) {
        int n = min(64, end - b);
        int myS = (lane < n) ? csr_send[b + lane] : 0;
        for (int i = 0; i < n; ++i) {
            int s = __shfl(myS, i);
            float4 x = *(const float4*)&X[(size_t)s * H_DIM + (lane << 2)];
            acc.x += x.x; acc.y += x.y; acc.z += x.z; acc.w += x.w;
        }
    }
    float ir = inv_r[node];
    float4 vv = *(const float4*)&v[lane << 2];
    float d = selu_f(acc.x * ir) * vv.x + selu_f(acc.y * ir) * vv.y
            + selu_f(acc.z * ir) * vv.z + selu_f(acc.w * ir) * vv.w;
    #pragma unroll
    for (int off = 32; off; off >>= 1) d += __shfl_down(d, off);
    if (lane == 0) out[node] = d;
}

__global__ __launch_bounds__(256) void k_colsum(const float* __restrict__ nodes1,
                                                float* __restrict__ colsum) {
    int t = threadIdx.x;
    size_t r0 = (size_t)blockIdx.x * 256;
    float s = 0.f;
    for (int r = 0; r < 256; ++r) s += nodes1[(r0 + r) * H_DIM + t];
    atomicAdd(&colsum[t], s);
}

__global__ void k_summary_v(const float* __restrict__ colsum, const float* __restrict__ Wb,
                            float* __restrict__ v) {
    __shared__ float s_sum[H_DIM];
    int t = threadIdx.x;
    float m = colsum[t] * (1.f / (float)N_NODES);
    s_sum[t] = 1.f / (1.f + expf(-m));
    __syncthreads();
    float acc = 0.f;
    for (int j = 0; j < H_DIM; ++j) acc += Wb[t * H_DIM + j] * s_sum[j];
    v[t] = acc;
}

// fused: logits[row]=dot(emb_row, v)  (pre-norm), then row-normalize in place + e2
__global__ __launch_bounds__(256) void k_normrow(
    float* __restrict__ emb, const float* __restrict__ v,
    float* __restrict__ logits, float* __restrict__ e2) {
    int row = blockIdx.x * 4 + (threadIdx.x >> 6);
    int lane = threadIdx.x & 63;
    float4 a = *(float4*)&emb[(size_t)row * H_DIM + (lane << 2)];
    float4 vv = *(const float4*)&v[lane << 2];
    float d = a.x * vv.x + a.y * vv.y + a.z * vv.z + a.w * vv.w;
    float ss = a.x * a.x + a.y * a.y + a.z * a.z + a.w * a.w;
    #pragma unroll
    for (int off = 32; off; off >>= 1) {
        d += __shfl_xor(d, off);
        ss += __shfl_xor(ss, off);
    }
    if (lane == 0) logits[row] = d;
    float inv = 1.f / sqrtf(ss);
    a.x *= inv; a.y *= inv; a.z *= inv; a.w *= inv;
    *(float4*)&emb[(size_t)row * H_DIM + (lane << 2)] = a;
    float s2 = a.x * a.x + a.y * a.y + a.z * a.z + a.w * a.w;
    #pragma unroll
    for (int off = 32; off; off >>= 1) s2 += __shfl_xor(s2, off);
    if (lane == 0) e2[row] = s2;
}

__global__ __launch_bounds__(256) void k_c2(const float* __restrict__ centers,
                                            float* __restrict__ c2) {
    int row = blockIdx.x * 4 + (threadIdx.x >> 6);
    int lane = threadIdx.x & 63;
    float4 a = *(const float4*)&centers[(size_t)row * H_DIM + (lane << 2)];
    float ss = a.x * a.x + a.y * a.y + a.z * a.z + a.w * a.w;
    #pragma unroll
    for (int off = 32; off; off >>= 1) ss += __shfl_xor(ss, off);
    if (lane == 0) c2[row] = ss;
}

#define DCOMP(ih, jh, i, comp, j) { \
    float d2_ = ev + c2v[jh].comp - 2.f * acc[ih][jh][i].comp; \
    float d_ = sqrtf(fmaxf(d2_, 1e-12f)); \
    rmin = fminf(rmin, d_); \
    unsigned long long pk_ = ((unsigned long long)__float_as_uint(d_) << 32) | (unsigned)row; \
    if (pk_ < cb[jh][j]) cb[jh][j] = pk_; }
#define DJH(ih, jh, i) \
    DCOMP(ih, jh, i, x, 0) DCOMP(ih, jh, i, y, 1) DCOMP(ih, jh, i, z, 2) DCOMP(ih, jh, i, w, 3)

// fused emb @ centers^T with min/argmin reductions; 128x128 tile, 8x8 split microtile
__global__ __launch_bounds__(256) void k_cluster128(
    const float* __restrict__ emb, const float* __restrict__ centers,
    const float* __restrict__ e2, const float* __restrict__ c2,
    unsigned* __restrict__ node_min, unsigned long long* __restrict__ center_min) {
    __shared__ float As[16][132];
    __shared__ float Bs[16][132];
    __shared__ unsigned s_nmin[128];
    __shared__ unsigned long long s_cmin[128];
    const int t = threadIdx.x;
    const int tm = t >> 4, tn = t & 15;
    const int m0 = blockIdx.x * 128;
    const int n0 = blockIdx.y * 128;
    const int sm = t >> 1;            // A-stage row 0..127
    const int sk = (t & 1) << 3;      // 0 or 8
    const int cn = t >> 2;            // B-stage center 0..63
    const int ck = (t & 3) << 2;      // 0,4,8,12
    float4 acc[2][2][4] = {};
    const float* Arow = emb + (size_t)(m0 + sm) * H_DIM;
    const float* C0 = centers + (size_t)(n0 + cn) * H_DIM;
    const float* C1 = centers + (size_t)(n0 + cn + 64) * H_DIM;
    for (int k0 = 0; k0 < H_DIM; k0 += 16) {
        float4 va = *(const float4*)&Arow[k0 + sk];
        float4 vb = *(const float4*)&Arow[k0 + sk + 4];
        As[sk + 0][sm] = va.x; As[sk + 1][sm] = va.y; As[sk + 2][sm] = va.z; As[sk + 3][sm] = va.w;
        As[sk + 4][sm] = vb.x; As[sk + 5][sm] = vb.y; As[sk + 6][sm] = vb.z; As[sk + 7][sm] = vb.w;
        float4 v0 = *(const float4*)&C0[k0 + ck];
        Bs[ck + 0][cn] = v0.x; Bs[ck + 1][cn] = v0.y; Bs[ck + 2][cn] = v0.z; Bs[ck + 3][cn] = v0.w;
        float4 v1 = *(const float4*)&C1[k0 + ck];
        Bs[ck + 0][cn + 64] = v1.x; Bs[ck + 1][cn + 64] = v1.y; Bs[ck + 2][cn + 64] = v1.z; Bs[ck + 3][cn + 64] = v1.w;
        __syncthreads();
        #pragma unroll
        for (int k = 0; k < 16; ++k) {
            float4 a0 = *(float4*)&As[k][tm << 2];
            float4 a1 = *(float4*)&As[k][64 + (tm << 2)];
            float4 b0 = *(float4*)&Bs[k][tn << 2];
            float4 b1 = *(float4*)&Bs[k][64 + (tn << 2)];
            MT(0, 0, a0, b0) MT(0, 1, a0, b1) MT(1, 0, a1, b0) MT(1, 1, a1, b1)
        }
        __syncthreads();
    }
    if (t < 128) { s_nmin[t] = 0x7F800000u; s_cmin[t] = ~0ull; }
    __syncthreads();
    float4 c2v[2];
    c2v[0] = *(const float4*)&c2[n0 + (tn << 2)];
    c2v[1] = *(const float4*)&c2[n0 + 64 + (tn << 2)];
    unsigned long long cb[2][4] = {{~0ull, ~0ull, ~0ull, ~0ull}, {~0ull, ~0ull, ~0ull, ~0ull}};
    #pragma unroll
    for (int ih = 0; ih < 2; ++ih)
        #pragma unroll
        for (int i = 0; i < 4; ++i) {
            int row = m0 + ih * 64 + (tm << 2) + i;
            float ev = e2[row];
            float rmin = 3.402823466e+38f;
            DJH(ih, 0, i) DJH(ih, 1, i)
            atomicMin(&s_nmin[ih * 64 + (tm << 2) + i], __float_as_uint(rmin));
        }
    #pragma unroll
    for (int jh = 0; jh < 2; ++jh)
        #pragma unroll
        for (int j = 0; j < 4; ++j)
            atomicMin(&s_cmin[jh * 64 + (tn << 2) + j], cb[jh][j]);
    __syncthreads();
    if (t < 128) {
        atomicMin(&node_min[m0 + t], s_nmin[t]);
        atomicMin(&center_min[n0 + t], s_cmin[t]);
    }
}

__global__ __launch_bounds__(256) void k_loss(const unsigned* __restrict__ node_min,
                                              double* __restrict__ acc) {
    int i = blockIdx.x * 256 + threadIdx.x;
    float s = __uint_as_float(node_min[i]);
    #pragma unroll
    for (int off = 32; off; off >>= 1) s += __shfl_down(s, off);
    __shared__ float ws[4];
    int lane = threadIdx.x & 63, w = threadIdx.x >> 6;
    if (lane == 0) ws[w] = s;
    __syncthreads();
    if (threadIdx.x == 0) {
        float tot = ws[0] + ws[1] + ws[2] + ws[3];
        atomicAdd(acc, (double)tot);
    }
}

__global__ void k_finalize(const unsigned long long* __restrict__ center_min,
                           const double* __restrict__ loss_acc,
                           float* __restrict__ rep_out, float* __restrict__ loss_out) {
    int t = blockIdx.x * 256 + threadIdx.x;
    if (t < R_REPS) rep_out[t] = (float)(unsigned)(center_min[t] & 0xFFFFFFFFull);
    if (t == 0) *loss_out = (float)(*loss_acc);
}

extern "C" void kernel_launch(void* const* d_in, const int* in_sizes, int n_in,
                              void* d_out, int out_size, void* d_ws, size_t ws_size,
                              hipStream_t stream) {
    const float* nodes   = (const float*)d_in[0];
    const float* c_nodes = (const float*)d_in[1];
    const int* senders   = (const int*)d_in[2];
    const int* receivers = (const int*)d_in[3];
    const float* W       = (const float*)d_in[4];
    const float* bias    = (const float*)d_in[5];
    const float* Wb      = (const float*)d_in[6];
    const float* centers = (const float*)d_in[7];

    float* out = (float*)d_out;
    float* out_emb    = out;                                  // N*H
    float* out_cent   = out + (size_t)N_NODES * H_DIM;        // R*H
    float* out_rep    = out_cent + (size_t)R_REPS * H_DIM;    // R
    float* out_loss   = out_rep + R_REPS;                     // 1
    float* out_logits = out_loss + 1;                         // 2N

    // ---- workspace: 8-byte-typed scratch first (alignment), then 4-byte arrays ----
    char* wp = (char*)d_ws;
    unsigned long long* center_min = (unsigned long long*)wp; wp += (size_t)R_REPS * 8;
    double* loss_acc = (double*)wp;             wp += 8;
    float* X = (float*)wp;                      wp += (size_t)N_NODES * H_DIM * 4;
    int* csr_send = (int*)wp;                   wp += (size_t)E_EDGES * 4;
    int* row_ptr = (int*)wp;                    wp += (size_t)(N_NODES + 2) * 4;
    int* cursor = (int*)wp;                     wp += (size_t)N_NODES * 4;
    int* cnt_s = (int*)wp;                      wp += (size_t)N_NODES * 4;
    int* cnt_r = (int*)wp;                      wp += (size_t)N_NODES * 4;
    float* inv_s = (float*)wp;                  wp += (size_t)N_NODES * 4;
    float* inv_r = (float*)wp;                  wp += (size_t)N_NODES * 4;
    float* colsum = (float*)wp;                 wp += (size_t)H_DIM * 4;
    float* v = (float*)wp;                      wp += (size_t)H_DIM * 4;
    float* e2 = (float*)wp;                     wp += (size_t)N_NODES * 4;
    float* c2 = (float*)wp;                     wp += (size_t)R_REPS * 4;
    unsigned* node_min = (unsigned*)wp;         wp += (size_t)N_NODES * 4;

    k_init<<<N_NODES / 256, 256, 0, stream>>>(cnt_s, cnt_r, cursor, colsum, node_min, center_min, loss_acc);
    k_degree<<<E_EDGES / 256, 256, 0, stream>>>(senders, receivers, cnt_s, cnt_r);
    k_invsqrt<<<N_NODES / 256, 256, 0, stream>>>(cnt_s, cnt_r, inv_s, inv_r);
    k_scan<<<1, 1024, 0, stream>>>(cnt_r, row_ptr);
    k_fill<<<E_EDGES / 256, 256, 0, stream>>>(senders, receivers, row_ptr, cursor, csr_send);

    dim3 gg(N_NODES / 128, H_DIM / 128);
    // GCN1
    k_gemm128<<<gg, 256, 0, stream>>>(nodes, W, bias, inv_s, X);
    k_agg1<<<N_NODES / 4, 256, 0, stream>>>(X, csr_send, row_ptr, inv_r, out_emb);

    k_colsum<<<N_NODES / 256, 256, 0, stream>>>(out_emb, colsum);
    k_summary_v<<<1, 256, 0, stream>>>(colsum, Wb, v);
    k_normrow<<<N_NODES / 4, 256, 0, stream>>>(out_emb, v, out_logits, e2);
    k_c2<<<R_REPS / 4, 256, 0, stream>>>(centers, c2);

    dim3 gc(N_NODES / 128, R_REPS / 128);
    k_cluster128<<<gc, 256, 0, stream>>>(out_emb, centers, e2, c2, node_min, center_min);
    k_loss<<<N_NODES / 256, 256, 0, stream>>>(node_min, loss_acc);
    k_finalize<<<2, 256, 0, stream>>>(center_min, loss_acc, out_rep, out_loss);
    hipMemcpyAsync(out_cent, centers, (size_t)R_REPS * H_DIM * 4, hipMemcpyDeviceToDevice, stream);

    // GCN2 (reuse X; nodes2 never materialized)
    k_gemm128<<<gg, 256, 0, stream>>>(c_nodes, W, bias, inv_s, X);
    k_agg2<<<N_NODES / 4, 256, 0, stream>>>(X, csr_send, row_ptr, inv_r, v, out_logits + N_NODES);
}